// Round 2
// baseline (245.752 us; speedup 1.0000x reference)
//
#include <hip/hip_runtime.h>
#include <hip/hip_bf16.h>
#include <stdint.h>

typedef _Float16 f16;
typedef _Float16 f16x8 __attribute__((ext_vector_type(8)));
typedef float f32x4 __attribute__((ext_vector_type(4)));

#define AS1 __attribute__((address_space(1)))
#define AS3 __attribute__((address_space(3)))

// ---------------------------------------------------------------------------
// Transpose + fp32->fp16 convert:  src [R][C] f32  ->  dst [C][R] f16
// grid: (C/64, R/64, batches), block 256
// ---------------------------------------------------------------------------
__global__ __launch_bounds__(256) void tr_cvt_kernel(
    const float* __restrict__ src, f16* __restrict__ dst, int R, int C)
{
    __shared__ float tile[64][65];
    const int b = blockIdx.z;
    src += (size_t)b * R * C;
    dst += (size_t)b * R * C;
    const int c0 = blockIdx.x * 64;
    const int r0 = blockIdx.y * 64;
    const int t = threadIdx.x;

    // phase 1: coalesced read 64x64 f32
    {
        const int cc = (t & 15) * 4;
        const int rr = t >> 4;
#pragma unroll
        for (int p = 0; p < 4; ++p) {
            const int r = rr + p * 16;
            const float4 v = *(const float4*)(src + (size_t)(r0 + r) * C + c0 + cc);
            tile[r][cc + 0] = v.x; tile[r][cc + 1] = v.y;
            tile[r][cc + 2] = v.z; tile[r][cc + 3] = v.w;
        }
    }
    __syncthreads();
    // phase 2: coalesced write 64x64 f16 transposed
    {
        const int rq = (t & 15) * 4;   // r-quad, fast dim of dst
        const int cp = t >> 4;
#pragma unroll
        for (int p = 0; p < 4; ++p) {
            const int c = cp + p * 16;
            ushort4 o;
            f16 h0 = (f16)tile[rq + 0][c];
            f16 h1 = (f16)tile[rq + 1][c];
            f16 h2 = (f16)tile[rq + 2][c];
            f16 h3 = (f16)tile[rq + 3][c];
            o.x = __builtin_bit_cast(unsigned short, h0);
            o.y = __builtin_bit_cast(unsigned short, h1);
            o.z = __builtin_bit_cast(unsigned short, h2);
            o.w = __builtin_bit_cast(unsigned short, h3);
            *(ushort4*)(dst + (size_t)(c0 + c) * R + r0 + rq) = o;
        }
    }
}

// ---------------------------------------------------------------------------
// C[M,N] = A[M,K] * Bt[N,K]^T   (both operands K-contiguous, f16)
// m97 structure: 128x128 tile, BK=64, 4 waves (each 64x64 = 4x4 frags),
// global_load_lds width-16 staging, mfma_f32_16x16x32_f16.
// grid: (N/128, M/128, batches), block 256
// ---------------------------------------------------------------------------
template <bool F32OUT>
__global__ __launch_bounds__(256) void gemm_abt(
    const f16* __restrict__ A, long long sAb,
    const f16* __restrict__ Bt, long long sBb,
    void* __restrict__ Cout, long long sCb,
    const float* __restrict__ bias,
    int M, int N, int K, int lda, int ldb, int ldc)
{
    __shared__ f16 As[128 * 64];
    __shared__ f16 Bs[128 * 64];
    const int b = blockIdx.z;
    A  += (size_t)b * sAb;
    Bt += (size_t)b * sBb;
    const int tn0 = blockIdx.x * 128;
    const int tm0 = blockIdx.y * 128;
    const int tid = threadIdx.x;
    const int lane = tid & 63, w = tid >> 6;
    const int wr = w >> 1, wc = w & 1;

    f32x4 acc[4][4];
#pragma unroll
    for (int i = 0; i < 4; ++i)
#pragma unroll
        for (int j = 0; j < 4; ++j) acc[i][j] = f32x4{0.f, 0.f, 0.f, 0.f};

    const int lrow = lane >> 3;        // 0..7
    const int lcol = (lane & 7) * 8;   // 0,8,..,56

    for (int k0 = 0; k0 < K; k0 += 64) {
#pragma unroll
        for (int p = 0; p < 4; ++p) {
            const f16* sa = A + (size_t)(tm0 + p * 32 + w * 8 + lrow) * lda + k0 + lcol;
            __builtin_amdgcn_global_load_lds(
                (const AS1 uint32_t*)sa,
                (AS3 uint32_t*)((char*)As + p * 4096 + w * 1024), 16, 0, 0);
            const f16* sb = Bt + (size_t)(tn0 + p * 32 + w * 8 + lrow) * ldb + k0 + lcol;
            __builtin_amdgcn_global_load_lds(
                (const AS1 uint32_t*)sb,
                (AS3 uint32_t*)((char*)Bs + p * 4096 + w * 1024), 16, 0, 0);
        }
        __syncthreads();
#pragma unroll
        for (int kk = 0; kk < 2; ++kk) {
            f16x8 af[4], bfr[4];
#pragma unroll
            for (int i = 0; i < 4; ++i)
                af[i] = *(const f16x8*)&As[(wr * 64 + i * 16 + (lane & 15)) * 64 + kk * 32 + (lane >> 4) * 8];
#pragma unroll
            for (int j = 0; j < 4; ++j)
                bfr[j] = *(const f16x8*)&Bs[(wc * 64 + j * 16 + (lane & 15)) * 64 + kk * 32 + (lane >> 4) * 8];
#pragma unroll
            for (int i = 0; i < 4; ++i)
#pragma unroll
                for (int j = 0; j < 4; ++j)
                    acc[i][j] = __builtin_amdgcn_mfma_f32_16x16x32_f16(af[i], bfr[j], acc[i][j], 0, 0, 0);
        }
        __syncthreads();
    }

    // epilogue: D[row=(lane>>4)*4+q][col=lane&15] per 16x16 frag
    const int r0 = tm0 + wr * 64;
    const int c0 = tn0 + wc * 64;
    const int cl = lane & 15, rg = lane >> 4;
    if (F32OUT) {
        float* C = (float*)Cout + (size_t)b * sCb;
#pragma unroll
        for (int i = 0; i < 4; ++i)
#pragma unroll
            for (int j = 0; j < 4; ++j) {
                const int cc = c0 + j * 16 + cl;
                const float bv = bias ? bias[cc] : 0.f;
#pragma unroll
                for (int q = 0; q < 4; ++q) {
                    const int rr = r0 + i * 16 + rg * 4 + q;
                    C[(size_t)rr * ldc + cc] = acc[i][j][q] + bv;
                }
            }
    } else {
        f16* C = (f16*)Cout + (size_t)b * sCb;
#pragma unroll
        for (int i = 0; i < 4; ++i)
#pragma unroll
            for (int j = 0; j < 4; ++j) {
                const int cc = c0 + j * 16 + cl;
#pragma unroll
                for (int q = 0; q < 4; ++q) {
                    const int rr = r0 + i * 16 + rg * 4 + q;
                    C[(size_t)rr * ldc + cc] = (f16)acc[i][j][q];
                }
            }
    }
}

// ---------------------------------------------------------------------------
// Per (b,h): dots = U_h * Wk_h^T, vv = W2_h * Wv2_h^T  (64x64, K=1024),
// softmax(dots*0.125) rows, out = attn @ vv, write O[b][r][h*64+f] (f16)
// grid: (16 heads, 8 batches), block 256 (4 waves)
// wave w: matrix = w>>1 (0 dots, 1 vv), K-half = w&1
// ---------------------------------------------------------------------------
__global__ __launch_bounds__(256) void attn_small(
    const f16* __restrict__ U, const f16* __restrict__ W2,
    const f16* __restrict__ WqkvT, f16* __restrict__ O)
{
    __shared__ float dots[64][66];
    __shared__ float vv[64][66];
    const int h = blockIdx.x, b = blockIdx.y;
    const int tid = threadIdx.x, lane = tid & 63, w = tid >> 6;
    const int isVV = w >> 1;
    const int kh = w & 1;

    const f16* Arows = (isVV ? W2 : U) + (size_t)b * (1024 * 1024) + (size_t)h * 64 * 1024;
    const f16* Brows = WqkvT + (size_t)(isVV ? 3072 : 1024) * 1024 + (size_t)h * 64 * 1024;

    f32x4 acc[4][4];
#pragma unroll
    for (int i = 0; i < 4; ++i)
#pragma unroll
        for (int j = 0; j < 4; ++j) acc[i][j] = f32x4{0.f, 0.f, 0.f, 0.f};

    const int cl = lane & 15, kg = lane >> 4;
    for (int ks = 0; ks < 16; ++ks) {
        const int k0 = kh * 512 + ks * 32 + kg * 8;
        f16x8 af[4], bfr[4];
#pragma unroll
        for (int i = 0; i < 4; ++i)
            af[i] = *(const f16x8*)(Arows + (size_t)(i * 16 + cl) * 1024 + k0);
#pragma unroll
        for (int j = 0; j < 4; ++j)
            bfr[j] = *(const f16x8*)(Brows + (size_t)(j * 16 + cl) * 1024 + k0);
#pragma unroll
        for (int i = 0; i < 4; ++i)
#pragma unroll
            for (int j = 0; j < 4; ++j)
                acc[i][j] = __builtin_amdgcn_mfma_f32_16x16x32_f16(af[i], bfr[j], acc[i][j], 0, 0, 0);
    }

    float (*dst)[66] = isVV ? vv : dots;
    if (kh == 0) {
#pragma unroll
        for (int i = 0; i < 4; ++i)
#pragma unroll
            for (int j = 0; j < 4; ++j)
#pragma unroll
                for (int q = 0; q < 4; ++q)
                    dst[i * 16 + kg * 4 + q][j * 16 + cl] = acc[i][j][q];
    }
    __syncthreads();
    if (kh == 1) {
#pragma unroll
        for (int i = 0; i < 4; ++i)
#pragma unroll
            for (int j = 0; j < 4; ++j)
#pragma unroll
                for (int q = 0; q < 4; ++q)
                    dst[i * 16 + kg * 4 + q][j * 16 + cl] += acc[i][j][q];
    }
    __syncthreads();

    // row softmax on dots (scale 0.125), threads 0..63 own one row each
    if (tid < 64) {
        const int r = tid;
        float mx = -1e30f;
        for (int e = 0; e < 64; ++e) {
            const float v = dots[r][e] * 0.125f;
            dots[r][e] = v;
            mx = fmaxf(mx, v);
        }
        float s = 0.f;
        for (int e = 0; e < 64; ++e) {
            const float v = __expf(dots[r][e] - mx);
            dots[r][e] = v;
            s += v;
        }
        const float inv = 1.f / s;
        for (int e = 0; e < 64; ++e) dots[r][e] *= inv;
    }
    __syncthreads();

    // out = attn @ vv; thread: row r = tid>>2, cols f0..f0+15
    {
        const int r = tid >> 2, f0 = (tid & 3) * 16;
        float o[16];
#pragma unroll
        for (int i = 0; i < 16; ++i) o[i] = 0.f;
        for (int e = 0; e < 64; ++e) {
            const float a = dots[r][e];
#pragma unroll
            for (int i = 0; i < 16; ++i) o[i] += a * vv[e][f0 + i];
        }
        f16* Od = O + (size_t)b * 64 * 1024 + (size_t)r * 1024 + h * 64 + f0;
#pragma unroll
        for (int i = 0; i < 16; ++i) Od[i] = (f16)o[i];
    }
}

// ---------------------------------------------------------------------------
extern "C" void kernel_launch(void* const* d_in, const int* in_sizes, int n_in,
                              void* d_out, int out_size, void* d_ws, size_t ws_size,
                              hipStream_t stream)
{
    const float* x    = (const float*)d_in[0];  // [8][4096][1024]
    const float* Wqkv = (const float*)d_in[1];  // [1024][4096]
    const float* Wout = (const float*)d_in[2];  // [1024][1024]
    const float* bout = (const float*)d_in[3];  // [1024]

    char* ws = (char*)d_ws;
    f16* xT    = (f16*)(ws + 0);           // [8][1024][4096]  67108864 B
    f16* WqkvT = (f16*)(ws + 67108864);    // [4096][1024]      8388608 B
    f16* WoutT = (f16*)(ws + 75497472);    // [1024][1024]      2097152 B
    f16* G     = (f16*)(ws + 77594624);    // [8][1024][1024]  16777216 B
    f16* U     = (f16*)(ws + 94371840);    // [8][1024][1024]  16777216 B
    f16* W2    = (f16*)(ws + 111149056);   // [8][1024][1024]  16777216 B
    f16* O     = (f16*)(ws + 127926272);   // [8][64][1024]     1048576 B

    // transposed f16 copies
    tr_cvt_kernel<<<dim3(16, 64, 8), 256, 0, stream>>>(x, xT, 4096, 1024);
    tr_cvt_kernel<<<dim3(64, 16, 1), 256, 0, stream>>>(Wqkv, WqkvT, 1024, 4096);
    tr_cvt_kernel<<<dim3(16, 16, 1), 256, 0, stream>>>(Wout, WoutT, 1024, 1024);

    // K1: G_b = x_b^T x_b  (A = xT rows, Bt = xT rows), M=N=1024, K=4096
    gemm_abt<false><<<dim3(8, 8, 8), 256, 0, stream>>>(
        xT, 4096LL * 1024, xT, 4096LL * 1024, G, 1024LL * 1024, nullptr,
        1024, 1024, 4096, 4096, 4096, 1024);

    // K2a: U = Wq^T G   (A = WqkvT rows 0..1023, Bt = G rows via symmetry)
    gemm_abt<false><<<dim3(8, 8, 8), 256, 0, stream>>>(
        WqkvT, 0LL, G, 1024LL * 1024, U, 1024LL * 1024, nullptr,
        1024, 1024, 1024, 1024, 1024, 1024);
    // K2b: W2 = Wv^T G  (A = WqkvT rows 2048..3071)
    gemm_abt<false><<<dim3(8, 8, 8), 256, 0, stream>>>(
        WqkvT + (size_t)2048 * 1024, 0LL, G, 1024LL * 1024, W2, 1024LL * 1024, nullptr,
        1024, 1024, 1024, 1024, 1024, 1024);

    // K3: per (b,h) small attention
    attn_small<<<dim3(16, 8), 256, 0, stream>>>(U, W2, WqkvT, O);

    // K4: out = O @ W_out + b_out  (M=512, N=1024, K=1024), fp32 out
    gemm_abt<true><<<dim3(8, 4, 1), 256, 0, stream>>>(
        O, 0LL, WoutT, 0LL, d_out, 0LL, bout,
        512, 1024, 1024, 1024, 1024, 1024);
}

// Round 3
// 227.362 us; speedup vs baseline: 1.0809x; 1.0809x over previous
//
#include <hip/hip_runtime.h>
#include <hip/hip_bf16.h>
#include <stdint.h>

typedef _Float16 f16;
typedef _Float16 f16x8 __attribute__((ext_vector_type(8)));
typedef float f32x4 __attribute__((ext_vector_type(4)));

#define AS1 __attribute__((address_space(1)))
#define AS3 __attribute__((address_space(3)))

// ---------------------------------------------------------------------------
// Transpose + fp32->fp16 convert:  src [R][C] f32  ->  dst [C][R] f16
// grid: (C/64, R/64, batches), block 256
// ---------------------------------------------------------------------------
__global__ __launch_bounds__(256) void tr_cvt_kernel(
    const float* __restrict__ src, f16* __restrict__ dst, int R, int C)
{
    __shared__ float tile[64][65];
    const int b = blockIdx.z;
    src += (size_t)b * R * C;
    dst += (size_t)b * R * C;
    const int c0 = blockIdx.x * 64;
    const int r0 = blockIdx.y * 64;
    const int t = threadIdx.x;
    {
        const int cc = (t & 15) * 4;
        const int rr = t >> 4;
#pragma unroll
        for (int p = 0; p < 4; ++p) {
            const int r = rr + p * 16;
            const float4 v = *(const float4*)(src + (size_t)(r0 + r) * C + c0 + cc);
            tile[r][cc + 0] = v.x; tile[r][cc + 1] = v.y;
            tile[r][cc + 2] = v.z; tile[r][cc + 3] = v.w;
        }
    }
    __syncthreads();
    {
        const int rq = (t & 15) * 4;
        const int cp = t >> 4;
#pragma unroll
        for (int p = 0; p < 4; ++p) {
            const int c = cp + p * 16;
            ushort4 o;
            f16 h0 = (f16)tile[rq + 0][c];
            f16 h1 = (f16)tile[rq + 1][c];
            f16 h2 = (f16)tile[rq + 2][c];
            f16 h3 = (f16)tile[rq + 3][c];
            o.x = __builtin_bit_cast(unsigned short, h0);
            o.y = __builtin_bit_cast(unsigned short, h1);
            o.z = __builtin_bit_cast(unsigned short, h2);
            o.w = __builtin_bit_cast(unsigned short, h3);
            *(ushort4*)(dst + (size_t)(c0 + c) * R + r0 + rq) = o;
        }
    }
}

// ---------------------------------------------------------------------------
// Common 128x128-tile, BK=64 GEMM body: C += A[128,K] * Bt[128,K]^T
// A/Bt point at tile origin. global_load_lds width-16 staging.
// ---------------------------------------------------------------------------
__device__ __forceinline__ void gemm_body(
    const f16* __restrict__ A, const f16* __restrict__ Bt,
    int lda, int ldb, int K, f16* As, f16* Bs,
    f32x4 (&acc)[4][4], int tid)
{
    const int lane = tid & 63, w = tid >> 6;
    const int wr = w >> 1, wc = w & 1;
    const int lrow = lane >> 3;
    const int lcol = (lane & 7) * 8;
    for (int k0 = 0; k0 < K; k0 += 64) {
#pragma unroll
        for (int p = 0; p < 4; ++p) {
            const f16* sa = A + (size_t)(p * 32 + w * 8 + lrow) * lda + k0 + lcol;
            __builtin_amdgcn_global_load_lds(
                (const AS1 uint32_t*)sa,
                (AS3 uint32_t*)((char*)As + p * 4096 + w * 1024), 16, 0, 0);
            const f16* sb = Bt + (size_t)(p * 32 + w * 8 + lrow) * ldb + k0 + lcol;
            __builtin_amdgcn_global_load_lds(
                (const AS1 uint32_t*)sb,
                (AS3 uint32_t*)((char*)Bs + p * 4096 + w * 1024), 16, 0, 0);
        }
        __syncthreads();
#pragma unroll
        for (int kk = 0; kk < 2; ++kk) {
            f16x8 af[4], bfr[4];
#pragma unroll
            for (int i = 0; i < 4; ++i)
                af[i] = *(const f16x8*)&As[(wr * 64 + i * 16 + (lane & 15)) * 64 + kk * 32 + (lane >> 4) * 8];
#pragma unroll
            for (int j = 0; j < 4; ++j)
                bfr[j] = *(const f16x8*)&Bs[(wc * 64 + j * 16 + (lane & 15)) * 64 + kk * 32 + (lane >> 4) * 8];
#pragma unroll
            for (int i = 0; i < 4; ++i)
#pragma unroll
                for (int j = 0; j < 4; ++j)
                    acc[i][j] = __builtin_amdgcn_mfma_f32_16x16x32_f16(af[i], bfr[j], acc[i][j], 0, 0, 0);
        }
        __syncthreads();
    }
}

// ---------------------------------------------------------------------------
// K1: upper-triangle tiles of G_b = xT_b * xT_b^T, split-K=4, f16 partials.
// grid: 1152 blocks 1D (36 tiles x 8 batch x 4 splits), XCD-chunked swizzle.
// Gp layout: [split][batch][blk][128][128] f16 (compact upper tiles)
// ---------------------------------------------------------------------------
__global__ __launch_bounds__(256) void gemm_syk(
    const f16* __restrict__ xT, f16* __restrict__ Gp)
{
    __shared__ f16 As[128 * 64];
    __shared__ f16 Bs[128 * 64];
    const int orig = blockIdx.x;
    const int l = (orig & 7) * 144 + (orig >> 3);   // 1152 = 8*144, bijective
    const int blk = l % 36;
    const int b = (l / 36) & 7;
    const int s = l / 288;
    int ti = 0, rem = blk;
    while (rem >= 8 - ti) { rem -= 8 - ti; ++ti; }
    const int tj = ti + rem;

    const f16* base = xT + (size_t)b * (1024 * 4096) + (size_t)s * 1024;
    const f16* A  = base + (size_t)ti * 128 * 4096;
    const f16* Bt = base + (size_t)tj * 128 * 4096;

    f32x4 acc[4][4];
#pragma unroll
    for (int i = 0; i < 4; ++i)
#pragma unroll
        for (int j = 0; j < 4; ++j) acc[i][j] = f32x4{0.f, 0.f, 0.f, 0.f};

    gemm_body(A, Bt, 4096, 4096, 1024, As, Bs, acc, threadIdx.x);

    f16* out = Gp + (((size_t)s * 8 + b) * 36 + blk) * 16384;
    const int lane = threadIdx.x & 63, w = threadIdx.x >> 6;
    const int wr = w >> 1, wc = w & 1;
    const int cl = lane & 15, rg = lane >> 4;
#pragma unroll
    for (int i = 0; i < 4; ++i)
#pragma unroll
        for (int j = 0; j < 4; ++j)
#pragma unroll
            for (int q = 0; q < 4; ++q) {
                const int row = wr * 64 + i * 16 + rg * 4 + q;
                const int col = wc * 64 + j * 16 + cl;
                out[row * 128 + col] = (f16)acc[i][j][q];
            }
}

// ---------------------------------------------------------------------------
// Sum 4 split partials -> G tile (f16) + mirrored transpose tile.
// grid: (36, 8), block 256. LDS 128x129 f32 for conflict-free transpose.
// ---------------------------------------------------------------------------
__global__ __launch_bounds__(256) void reduce_mirror(
    const f16* __restrict__ Gp, f16* __restrict__ G)
{
    __shared__ float tile[128][129];
    const int blk = blockIdx.x, b = blockIdx.y;
    int ti = 0, rem = blk;
    while (rem >= 8 - ti) { rem -= 8 - ti; ++ti; }
    const int tj = ti + rem;
    const size_t tb = ((size_t)b * 36 + blk) * 16384;
    const size_t sstride = (size_t)8 * 36 * 16384;
    f16* Gb = G + (size_t)b * (1024 * 1024);
    const int t = threadIdx.x;

#pragma unroll
    for (int i = 0; i < 8; ++i) {
        const int e = (i * 256 + t) * 8;
        const int r = e >> 7, c = e & 127;
        float sum[8];
#pragma unroll
        for (int j = 0; j < 8; ++j) sum[j] = 0.f;
#pragma unroll
        for (int sp = 0; sp < 4; ++sp) {
            const f16x8 v = *(const f16x8*)(Gp + sp * sstride + tb + e);
#pragma unroll
            for (int j = 0; j < 8; ++j) sum[j] += (float)v[j];
        }
        f16x8 o;
#pragma unroll
        for (int j = 0; j < 8; ++j) {
            o[j] = (f16)sum[j];
            tile[r][c + j] = sum[j];
        }
        *(f16x8*)(Gb + (size_t)(ti * 128 + r) * 1024 + tj * 128 + c) = o;
    }
    if (ti != tj) {
        __syncthreads();
#pragma unroll
        for (int i = 0; i < 8; ++i) {
            const int e = (i * 256 + t) * 8;
            const int R = e >> 7, C = e & 127;
            f16x8 o;
#pragma unroll
            for (int j = 0; j < 8; ++j) o[j] = (f16)tile[C + j][R];
            *(f16x8*)(Gb + (size_t)(tj * 128 + R) * 1024 + ti * 128 + C) = o;
        }
    }
}

// ---------------------------------------------------------------------------
// K2 fused: UW2[b][0..1023]   = Wq^T G_b   (rows 0..1023 of WqkvT)
//           UW2[b][1024..2047] = Wv^T G_b  (rows 2048..3071 of WqkvT)
// grid: 1024 blocks 1D (8 N-tiles x 16 M-tiles x 8 batch), XCD swizzle.
// ---------------------------------------------------------------------------
__global__ __launch_bounds__(256) void gemm_qv(
    const f16* __restrict__ WqkvT, const f16* __restrict__ G,
    f16* __restrict__ UW2)
{
    __shared__ f16 As[128 * 64];
    __shared__ f16 Bs[128 * 64];
    const int orig = blockIdx.x;
    const int l = (orig & 7) * 128 + (orig >> 3);   // 1024 = 8*128, bijective
    const int bx = l & 7, by = (l >> 3) & 15, b = l >> 7;
    const int tm0 = by * 128, tn0 = bx * 128;
    const int arow = (tm0 < 1024) ? tm0 : tm0 + 1024;   // skip Wk region

    const f16* A  = WqkvT + (size_t)arow * 1024;
    const f16* Bt = G + (size_t)b * (1024 * 1024) + (size_t)tn0 * 1024;

    f32x4 acc[4][4];
#pragma unroll
    for (int i = 0; i < 4; ++i)
#pragma unroll
        for (int j = 0; j < 4; ++j) acc[i][j] = f32x4{0.f, 0.f, 0.f, 0.f};

    gemm_body(A, Bt, 1024, 1024, 1024, As, Bs, acc, threadIdx.x);

    f16* C = UW2 + (size_t)b * (2048 * 1024);
    const int lane = threadIdx.x & 63, w = threadIdx.x >> 6;
    const int wr = w >> 1, wc = w & 1;
    const int cl = lane & 15, rg = lane >> 4;
#pragma unroll
    for (int i = 0; i < 4; ++i)
#pragma unroll
        for (int j = 0; j < 4; ++j) {
            const int cc = tn0 + wc * 64 + j * 16 + cl;
#pragma unroll
            for (int q = 0; q < 4; ++q) {
                const int rr = tm0 + wr * 64 + i * 16 + rg * 4 + q;
                C[(size_t)rr * 1024 + cc] = (f16)acc[i][j][q];
            }
        }
}

// ---------------------------------------------------------------------------
// K4: C[M,N] f32 = A[M,K] * Bt[N,K]^T + bias  (generic, small use)
// ---------------------------------------------------------------------------
__global__ __launch_bounds__(256) void gemm_out(
    const f16* __restrict__ A, const f16* __restrict__ Bt,
    float* __restrict__ Cout, const float* __restrict__ bias,
    int K, int lda, int ldb, int ldc)
{
    __shared__ f16 As[128 * 64];
    __shared__ f16 Bs[128 * 64];
    const int tn0 = blockIdx.x * 128;
    const int tm0 = blockIdx.y * 128;
    f32x4 acc[4][4];
#pragma unroll
    for (int i = 0; i < 4; ++i)
#pragma unroll
        for (int j = 0; j < 4; ++j) acc[i][j] = f32x4{0.f, 0.f, 0.f, 0.f};

    gemm_body(A + (size_t)tm0 * lda, Bt + (size_t)tn0 * ldb, lda, ldb, K,
              As, Bs, acc, threadIdx.x);

    const int lane = threadIdx.x & 63, w = threadIdx.x >> 6;
    const int wr = w >> 1, wc = w & 1;
    const int cl = lane & 15, rg = lane >> 4;
#pragma unroll
    for (int i = 0; i < 4; ++i)
#pragma unroll
        for (int j = 0; j < 4; ++j) {
            const int cc = tn0 + wc * 64 + j * 16 + cl;
            const float bv = bias[cc];
#pragma unroll
            for (int q = 0; q < 4; ++q) {
                const int rr = tm0 + wr * 64 + i * 16 + rg * 4 + q;
                Cout[(size_t)rr * ldc + cc] = acc[i][j][q] + bv;
            }
        }
}

// ---------------------------------------------------------------------------
// Per (b,h): dots = U_h * Wk_h^T, vv = W2_h * Wv2_h^T  (64x64, K=1024),
// softmax(dots*0.125), out = attn @ vv -> O[b][r][h*64+f] (f16)
// grid: (16 heads, 8 batches), block 256
// ---------------------------------------------------------------------------
__global__ __launch_bounds__(256) void attn_small(
    const f16* __restrict__ UW2, const f16* __restrict__ WqkvT,
    f16* __restrict__ O)
{
    __shared__ float dots[64][66];
    __shared__ float vv[64][66];
    const int h = blockIdx.x, b = blockIdx.y;
    const int tid = threadIdx.x, lane = tid & 63, w = tid >> 6;
    const int isVV = w >> 1;
    const int kh = w & 1;

    const f16* Arows = UW2 + (size_t)b * (2048 * 1024)
                           + (size_t)isVV * (1024 * 1024) + (size_t)h * 64 * 1024;
    const f16* Brows = WqkvT + (size_t)(isVV ? 3072 : 1024) * 1024 + (size_t)h * 64 * 1024;

    f32x4 acc[4][4];
#pragma unroll
    for (int i = 0; i < 4; ++i)
#pragma unroll
        for (int j = 0; j < 4; ++j) acc[i][j] = f32x4{0.f, 0.f, 0.f, 0.f};

    const int cl = lane & 15, kg = lane >> 4;
    for (int ks = 0; ks < 16; ++ks) {
        const int k0 = kh * 512 + ks * 32 + kg * 8;
        f16x8 af[4], bfr[4];
#pragma unroll
        for (int i = 0; i < 4; ++i)
            af[i] = *(const f16x8*)(Arows + (size_t)(i * 16 + cl) * 1024 + k0);
#pragma unroll
        for (int j = 0; j < 4; ++j)
            bfr[j] = *(const f16x8*)(Brows + (size_t)(j * 16 + cl) * 1024 + k0);
#pragma unroll
        for (int i = 0; i < 4; ++i)
#pragma unroll
            for (int j = 0; j < 4; ++j)
                acc[i][j] = __builtin_amdgcn_mfma_f32_16x16x32_f16(af[i], bfr[j], acc[i][j], 0, 0, 0);
    }

    float (*dst)[66] = isVV ? vv : dots;
    if (kh == 0) {
#pragma unroll
        for (int i = 0; i < 4; ++i)
#pragma unroll
            for (int j = 0; j < 4; ++j)
#pragma unroll
                for (int q = 0; q < 4; ++q)
                    dst[i * 16 + kg * 4 + q][j * 16 + cl] = acc[i][j][q];
    }
    __syncthreads();
    if (kh == 1) {
#pragma unroll
        for (int i = 0; i < 4; ++i)
#pragma unroll
            for (int j = 0; j < 4; ++j)
#pragma unroll
                for (int q = 0; q < 4; ++q)
                    dst[i * 16 + kg * 4 + q][j * 16 + cl] += acc[i][j][q];
    }
    __syncthreads();

    if (tid < 64) {
        const int r = tid;
        float mx = -1e30f;
        for (int e = 0; e < 64; ++e) {
            const float v = dots[r][e] * 0.125f;
            dots[r][e] = v;
            mx = fmaxf(mx, v);
        }
        float s = 0.f;
        for (int e = 0; e < 64; ++e) {
            const float v = __expf(dots[r][e] - mx);
            dots[r][e] = v;
            s += v;
        }
        const float inv = 1.f / s;
        for (int e = 0; e < 64; ++e) dots[r][e] *= inv;
    }
    __syncthreads();

    {
        const int r = tid >> 2, f0 = (tid & 3) * 16;
        float o[16];
#pragma unroll
        for (int i = 0; i < 16; ++i) o[i] = 0.f;
        for (int e = 0; e < 64; ++e) {
            const float a = dots[r][e];
#pragma unroll
            for (int i = 0; i < 16; ++i) o[i] += a * vv[e][f0 + i];
        }
        f16* Od = O + (size_t)b * 64 * 1024 + (size_t)r * 1024 + h * 64 + f0;
#pragma unroll
        for (int i = 0; i < 16; ++i) Od[i] = (f16)o[i];
    }
}

// ---------------------------------------------------------------------------
extern "C" void kernel_launch(void* const* d_in, const int* in_sizes, int n_in,
                              void* d_out, int out_size, void* d_ws, size_t ws_size,
                              hipStream_t stream)
{
    const float* x    = (const float*)d_in[0];  // [8][4096][1024]
    const float* Wqkv = (const float*)d_in[1];  // [1024][4096]
    const float* Wout = (const float*)d_in[2];  // [1024][1024]
    const float* bout = (const float*)d_in[3];  // [1024]

    char* ws = (char*)d_ws;
    f16* xT    = (f16*)(ws + 0);           // [8][1024][4096]   67108864 B
    f16* WqkvT = (f16*)(ws + 67108864);    // [4096][1024]       8388608 B
    f16* WoutT = (f16*)(ws + 75497472);    // [1024][1024]       2097152 B
    f16* G     = (f16*)(ws + 77594624);    // [8][1024][1024]   16777216 B
    f16* Gp    = (f16*)(ws + 94371840);    // [4][8][36][16384] 37748736 B (union w/ UW2)
    f16* UW2   = (f16*)(ws + 94371840);    // [8][2048][1024]   33554432 B
    f16* O     = (f16*)(ws + 132120576);   // [8][64][1024]      1048576 B

    tr_cvt_kernel<<<dim3(16, 64, 8), 256, 0, stream>>>(x, xT, 4096, 1024);
    tr_cvt_kernel<<<dim3(64, 16, 1), 256, 0, stream>>>(Wqkv, WqkvT, 1024, 4096);
    tr_cvt_kernel<<<dim3(16, 16, 1), 256, 0, stream>>>(Wout, WoutT, 1024, 1024);

    // K1: symmetric split-K upper tiles -> Gp
    gemm_syk<<<1152, 256, 0, stream>>>(xT, Gp);
    // reduce partials + mirror -> G
    reduce_mirror<<<dim3(36, 8), 256, 0, stream>>>(Gp, G);
    // K2 fused: UW2 = [Wq^T G ; Wv^T G]
    gemm_qv<<<1024, 256, 0, stream>>>(WqkvT, G, UW2);
    // K3: per (b,h) small attention
    attn_small<<<dim3(16, 8), 256, 0, stream>>>(UW2, WqkvT, O);
    // K4: out = O @ W_out^T(-transposed copy) + b_out
    gemm_out<<<dim3(8, 4), 256, 0, stream>>>(O, WoutT, (float*)d_out, bout,
                                             1024, 1024, 1024, 1024);
}